// Round 11
// baseline (3083.386 us; speedup 1.0000x reference)
//
#include <hip/hip_runtime.h>
#include <hip/hip_bf16.h>

#define DEV __device__ __forceinline__
typedef unsigned short u16;
typedef short bf16x8 __attribute__((ext_vector_type(8)));
typedef float f32x4  __attribute__((ext_vector_type(4)));

static constexpr float LOG2E = 1.44269504088896340736f;
static constexpr float C2E   = 2.88539008177792681472f; // 2*log2(e)

DEV float rcpf_(float x){ return __builtin_amdgcn_rcpf(x); }
DEV float exp2f_(float x){ return __builtin_amdgcn_exp2f(x); }
DEV float sigmoidf_(float x){ return rcpf_(1.f + exp2f_(-LOG2E*x)); }
DEV float tanhf_fast(float x){ return 1.f - 2.f*rcpf_(exp2f_(C2E*x) + 1.f); }
DEV u16 bfu(float f){
  __hip_bfloat16 h = __float2bfloat16(f);
  union { __hip_bfloat16 h; u16 u; } c; c.h = h; return c.u;
}
DEV float ubf_lo(unsigned u){ return __uint_as_float(u << 16); }
DEV float ubf_hi(unsigned u){ return __uint_as_float(u & 0xffff0000u); }
DEV unsigned pack2(float a, float b){ return (unsigned)bfu(a) | ((unsigned)bfu(b) << 16); }
DEV float ubf(u16 u){ return __uint_as_float(((unsigned)u) << 16); }

// 4-way batched reciprocal accumulate: s += sum_i v[i] / (f[i]*e[i]+1)
DEV void acc4inv(const float4 f, const float4 e, const float4 v, float& s){
  const float dx = __builtin_fmaf(f.x, e.x, 1.f);
  const float dy = __builtin_fmaf(f.y, e.y, 1.f);
  const float dz = __builtin_fmaf(f.z, e.z, 1.f);
  const float dw = __builtin_fmaf(f.w, e.w, 1.f);
  const float p2 = dx*dy, p3 = p2*dz, p4 = p3*dw;
  const float r4 = rcpf_(p4);
  const float iw = r4*p3;
  const float s3 = r4*dw;
  const float iz = s3*p2;
  const float s2 = s3*dz;
  const float iy = s2*dx;
  const float ix = s2*dy;
  s += v.x*ix; s += v.y*iy; s += v.z*iz; s += v.w*iw;
}

// ---------------------------------------------------------------------------
// K0: convert Wg (512x512), wih_f (384x512), wih_r (384x512) f32 -> bf16.
// ---------------------------------------------------------------------------
__global__ __launch_bounds__(256) void k_cvtw(const float* __restrict__ Wg,
      const float* __restrict__ wf, const float* __restrict__ wr,
      u16* __restrict__ out){
  const int i = (blockIdx.x*256 + threadIdx.x)*4;
  const float* src;
  int off;
  if (i < 262144){ src = Wg; off = i; }
  else if (i < 458752){ src = wf; off = i - 262144; }
  else { src = wr; off = i - 458752; }
  const float4 v = *(const float4*)(src + off);
  uint2 o; o.x = pack2(v.x, v.y); o.y = pack2(v.z, v.w);
  *(uint2*)(out + i) = o;
}

// ---------------------------------------------------------------------------
// K1: out[r*128+h] = exp(2*(pe[r,:]·W[h,:] + b[h])), r = l*64+b flat.
// 2 h-cols x 8 rows per thread: halves LDS x-tile reads vs 1-col x 16-row.
// ---------------------------------------------------------------------------
__global__ __launch_bounds__(256,4) void k_proj(const float* __restrict__ pe,
      const float* __restrict__ Wp, const float* __restrict__ Wpb,
      const float* __restrict__ Wph, const float* __restrict__ Wphb,
      float* __restrict__ E, float* __restrict__ F){
  __shared__ __align__(16) float xs[32*256];
  const int tid = threadIdx.x;
  const int sel = blockIdx.x >> 11;
  const long r0 = (long)(blockIdx.x & 2047) * 32;
  const float* W   = sel ? Wph  : Wp;
  const float* bia = sel ? Wphb : Wpb;
  float* out       = sel ? F    : E;
  const float4* src = (const float4*)(pe + r0*256);
  float4* dst = (float4*)xs;
  #pragma unroll
  for (int i=0;i<8;i++) dst[tid + 256*i] = src[tid + 256*i];
  __syncthreads();
  const int hp = (tid & 63)*2, rg = tid >> 6;   // h pair, row group (8 rows)
  float acc[2][8];
  #pragma unroll
  for (int c=0;c<2;c++)
    #pragma unroll
    for (int r=0;r<8;r++) acc[c][r] = 0.f;
  for (int kc=0; kc<8; kc++){
    float4 w0[8], w1[8];
    const float4* wp0 = (const float4*)(W + (long)hp*256 + kc*32);
    const float4* wp1 = (const float4*)(W + (long)(hp+1)*256 + kc*32);
    #pragma unroll
    for (int q=0;q<8;q++){ w0[q] = wp0[q]; w1[q] = wp1[q]; }
    #pragma unroll
    for (int r=0;r<8;r++){
      const float4* xr = (const float4*)(xs + (rg*8+r)*256 + kc*32);
      float a0 = 0.f, a1 = 0.f;
      #pragma unroll
      for (int q=0;q<8;q++){
        const float4 xv = xr[q];
        a0 += xv.x*w0[q].x + xv.y*w0[q].y + xv.z*w0[q].z + xv.w*w0[q].w;
        a1 += xv.x*w1[q].x + xv.y*w1[q].y + xv.z*w1[q].z + xv.w*w1[q].w;
      }
      acc[0][r] += a0; acc[1][r] += a1;
    }
  }
  const float b0 = bia[hp], b1 = bia[hp+1];
  #pragma unroll
  for (int r=0;r<8;r++){
    float2 o;
    o.x = exp2f_(C2E*(acc[0][r] + b0));
    o.y = exp2f_(C2E*(acc[1][r] + b1));
    *(float2*)(out + (r0 + rg*8 + r)*128 + hp) = o;
  }
}

// ---------------------------------------------------------------------------
// K2: fused attention. Block = (b, 64-t tile), 512 threads (8 waves).
// Phase S: lane covers 4t x 4l x 32h; h-partials combined fully in-register
// (shfl_xor 16 then 32); lanes hg==0 write the S region. Phase C via MFMA.
// ---------------------------------------------------------------------------
#define AF_F    0        // [64][132] f32  (reused as Cb u16[64][264] at end)
#define AF_E    8448     // [32][132] f32
#define AF_PEt  12672    // u16[256][40] transposed PE tile (5120 f32 slots)
#define AF_S    17792    // [64][33] f32  (P u16[64][40] overlays this region)
#define AF_V    19904    // [128]
#define AF_M    20032    // [64]
#define AF_SU   20096    // [64]
#define AF_R    20160    // [64]
#define A_LDSF  20224    // 80896 bytes -> 2 blocks/CU

DEV f32x4 mfma16(bf16x8 a, bf16x8 b, f32x4 c){
  return __builtin_amdgcn_mfma_f32_16x16x32_bf16(a, b, c, 0, 0, 0);
}

__global__ __launch_bounds__(512,4) void k_attn(const float* __restrict__ pe,
      const float* __restrict__ E, const float* __restrict__ F,
      const float* __restrict__ Vt, u16* __restrict__ Cout){
  __shared__ __align__(16) float lds[A_LDSF];
  const int tid = threadIdx.x;
  const int p = blockIdx.x;
  const int b = ((p >> 7) << 3) | (p & 7);   // XCD swizzle: same-b co-located
  const int tt = (p >> 3) & 15;
  const int t0 = tt * 64;
  u16* PEtu = (u16*)(lds + AF_PEt);
  u16* Pu   = (u16*)(lds + AF_S);

  // stage F tile [64][132], v' = -2v, init m/su
  for (int i = tid; i < 64*32; i += 512){
    const int r = i >> 5, c = i & 31;
    *(float4*)(lds + AF_F + r*132 + c*4) =
      *(const float4*)(F + ((long)(t0+r)*64 + b)*128 + c*4);
  }
  if (tid < 128) lds[AF_V + tid] = -2.f * Vt[b*128 + tid];
  if (tid < 64){ lds[AF_M+tid] = -__builtin_inff(); lds[AF_SU+tid] = 0.f; }

  f32x4 cacc[8];
  #pragma unroll
  for (int i=0;i<8;i++) cacc[i] = (f32x4){0.f,0.f,0.f,0.f};

  const int lane = tid & 63, w = tid >> 6;
  const int hg = lane >> 4, li = lane & 15;   // S-phase: h-group + tuple lane
  const int th = li & 1, lq = li >> 1;        // t-half, l-quad
  const int l15 = lane & 15, kg8 = (lane >> 4) * 8;  // MFMA frag mapping
  const int tq = w >> 1, dhalf = w & 1;
  const int tcol = tq*16 + l15;
  // PEt staging decomposition
  const int sdlo = tid & 7, slp = (tid >> 3) & 15, sdhi = tid >> 7;

  for (int lt=0; lt<32; lt++){
    const int l0 = lt*32;
    __syncthreads();  // prev phase-C / softmax reads done before staging
    for (int i = tid; i < 32*32; i += 512){
      const int r = i >> 5, c = i & 31;
      *(float4*)(lds + AF_E + r*132 + c*4) =
        *(const float4*)(E + ((long)(l0+r)*64 + b)*128 + c*4);
    }
    // stage PEt[d][l] bf16 (transposed, pair-packed)
    #pragma unroll
    for (int k2=0;k2<2;k2++){
      const int dseg = (sdhi + k2*4)*8 + sdlo;    // 0..63 (float4 col)
      const int ll = slp*2;
      const float4 vA = *(const float4*)(pe + ((long)(l0+ll  )*64 + b)*256 + dseg*4);
      const float4 vB = *(const float4*)(pe + ((long)(l0+ll+1)*64 + b)*256 + dseg*4);
      u16* base = PEtu + (dseg*4)*40 + ll;
      *(unsigned*)(base)        = pack2(vA.x, vB.x);
      *(unsigned*)(base + 40)   = pack2(vA.y, vB.y);
      *(unsigned*)(base + 80)   = pack2(vA.z, vB.z);
      *(unsigned*)(base + 120)  = pack2(vA.w, vB.w);
    }
    __syncthreads();
    // phase S: 4t x 4l x 32h per lane; t rows w*8+th+2i, l rows lq+8j
    {
      float s[4][4];
      #pragma unroll
      for (int i=0;i<4;i++)
        #pragma unroll
        for (int j=0;j<4;j++) s[i][j] = 0.f;
      const float* Fb = lds + AF_F + (w*8 + th)*132 + hg*32;
      const float* Eb = lds + AF_E + lq*132 + hg*32;
      const float* Vb = lds + AF_V + hg*32;
      #pragma unroll 2
      for (int hc=0; hc<8; hc++){
        const float4 vv = *(const float4*)(Vb + hc*4);
        float4 fv[4], ev[4];
        #pragma unroll
        for (int i=0;i<4;i++) fv[i] = *(const float4*)(Fb + i*264 + hc*4);
        #pragma unroll
        for (int j=0;j<4;j++) ev[j] = *(const float4*)(Eb + j*1056 + hc*4);
        #pragma unroll
        for (int i=0;i<4;i++){
          #pragma unroll
          for (int j=0;j<4;j++)
            acc4inv(fv[i], ev[j], vv, s[i][j]);
        }
      }
      // combine the 4 h-group partials fully in-register
      #pragma unroll
      for (int i=0;i<4;i++)
        #pragma unroll
        for (int j=0;j<4;j++){
          s[i][j] += __shfl_xor(s[i][j], 16);
          s[i][j] += __shfl_xor(s[i][j], 32);
        }
      if (hg == 0){
        #pragma unroll
        for (int i=0;i<4;i++)
          #pragma unroll
          for (int j=0;j<4;j++)
            lds[AF_S + (w*8 + th + 2*i)*33 + (lq + 8*j)] = s[i][j];
      }
    }
    __syncthreads();
    // online softmax; P written bf16 over the S region (barrier between)
    {
      const int t = tid >> 3, sub = tid & 7;
      const float* Srow = lds + AF_S + t*33 + sub*4;
      const float s0=Srow[0], s1=Srow[1], s2=Srow[2], s3=Srow[3];
      float mx = fmaxf(fmaxf(s0,s1), fmaxf(s2,s3));
      #pragma unroll
      for (int off=1; off<8; off<<=1) mx = fmaxf(mx, __shfl_xor(mx, off));
      const float m_old = lds[AF_M + t];
      const float m_new = fmaxf(m_old, mx);
      const float p0 = exp2f_(LOG2E*(s0-m_new));
      const float p1 = exp2f_(LOG2E*(s1-m_new));
      const float p2 = exp2f_(LOG2E*(s2-m_new));
      const float p3 = exp2f_(LOG2E*(s3-m_new));
      float ps = p0+p1+p2+p3;
      #pragma unroll
      for (int off=1; off<8; off<<=1) ps += __shfl_xor(ps, off);
      __syncthreads();   // all S reads done before P overwrites the region
      uint2 pw; pw.x = pack2(p0,p1); pw.y = pack2(p2,p3);
      *(uint2*)(Pu + t*40 + sub*4) = pw;
      if (sub==0){
        const float rsc = exp2f_(LOG2E*(m_old - m_new));
        lds[AF_R + t] = rsc;
        lds[AF_SU + t] = lds[AF_SU + t]*rsc + ps;
        lds[AF_M + t] = m_new;
      }
    }
    __syncthreads();
    // phase C (MFMA): rescale acc, then D[d][t] += PEt · P^T
    {
      const float rs = lds[AF_R + tcol];
      #pragma unroll
      for (int p2=0;p2<8;p2++){
        cacc[p2][0]*=rs; cacc[p2][1]*=rs; cacc[p2][2]*=rs; cacc[p2][3]*=rs;
      }
      const bf16x8 bfrag = *(const bf16x8*)(Pu + tcol*40 + kg8);
      #pragma unroll
      for (int p2=0;p2<8;p2++){
        const int dt = dhalf*8 + p2;
        const bf16x8 afrag = *(const bf16x8*)(PEtu + (dt*16 + l15)*40 + kg8);
        cacc[p2] = mfma16(afrag, bfrag, cacc[p2]);
      }
    }
  }
  // epilogue: normalize, bounce C^T through LDS (F region), coalesced store
  __syncthreads();
  {
    const float inv = rcpf_(lds[AF_SU + tcol]);
    u16* Cb = (u16*)(lds + AF_F);   // [64][264]
    const int rb = (lane >> 4) * 4;
    #pragma unroll
    for (int p2=0;p2<8;p2++){
      const int dd = (dhalf*8 + p2)*16 + rb;
      *(unsigned*)(Cb + tcol*264 + dd)     = pack2(cacc[p2][0]*inv, cacc[p2][1]*inv);
      *(unsigned*)(Cb + tcol*264 + dd + 2) = pack2(cacc[p2][2]*inv, cacc[p2][3]*inv);
    }
  }
  __syncthreads();
  {
    const u16* Cb = (const u16*)(lds + AF_F);
    #pragma unroll
    for (int k2=0;k2<4;k2++){
      const int flat = tid + k2*512;
      const int t = flat >> 5, dg = flat & 31;
      const uint4 v = *(const uint4*)(Cb + t*264 + dg*8);
      *(uint4*)(Cout + ((long)(t0+t)*64 + b)*256 + dg*8) = v;
    }
  }
}

// ---------------------------------------------------------------------------
// K3: MFMA gates, 8 waves (512 thr), 32 rows/block.
// ---------------------------------------------------------------------------
__global__ __launch_bounds__(512,2) void k_gates(const float* __restrict__ pe,
      const u16* __restrict__ Cin,
      const u16* __restrict__ Wgb16, const float* __restrict__ Wgb,
      const u16* __restrict__ wfb16, const float* __restrict__ bihf,
      const u16* __restrict__ wrb16, const float* __restrict__ bihr,
      u16* __restrict__ GIf, u16* __restrict__ GIr){
  __shared__ __align__(16) u16 ccb[32*512];
  __shared__ __align__(16) u16 gb [32*512];
  const int tid = threadIdx.x;
  const int r0 = blockIdx.x * 32;

  #pragma unroll
  for (int i=0;i<4;i++){
    const int c = tid + i*512;
    const int r = c >> 6, k0 = (c & 63)*8;
    const int kd = k0 ^ ((r&7)<<3);
    uint4 o;
    if (k0 < 256){
      const float4 f0 = *(const float4*)(pe + ((long)(r0+r))*256 + k0);
      const float4 f1 = *(const float4*)(pe + ((long)(r0+r))*256 + k0 + 4);
      o.x = pack2(f0.x,f0.y); o.y = pack2(f0.z,f0.w);
      o.z = pack2(f1.x,f1.y); o.w = pack2(f1.z,f1.w);
    } else {
      o = *(const uint4*)(Cin + ((long)(r0+r))*256 + (k0-256));
    }
    *(uint4*)(ccb + r*512 + kd) = o;
  }
  __syncthreads();

  const int l = tid & 63, wv = tid >> 6;   // 8 waves
  const int rw = (wv >> 2) * 16;           // row half
  const int nq = wv & 3;                   // col quarter
  const int arow = rw + (l & 15);
  const int kgrp = (l >> 4) * 8;
  const int swz  = (l & 7) << 3;
  const u16* abase = ccb + arow*512;
  const int crow = rw + (l >> 4) * 4;

  for (int p2=0; p2<4; p2++){
    const int n0 = nq*128 + p2*32;
    const int c0 = n0 + (l & 15), c1 = c0 + 16;
    const u16* b0p = Wgb16 + (long)c0*512 + kgrp;
    const u16* b1p = Wgb16 + (long)c1*512 + kgrp;
    f32x4 a0 = {0.f,0.f,0.f,0.f}, a1 = {0.f,0.f,0.f,0.f};
    #pragma unroll
    for (int kk=0; kk<16; kk++){
      const bf16x8 av = *(const bf16x8*)(abase + ((kk*32 + kgrp) ^ swz));
      const bf16x8 b0 = *(const bf16x8*)(b0p + kk*32);
      const bf16x8 b1 = *(const bf16x8*)(b1p + kk*32);
      a0 = mfma16(av, b0, a0);
      a1 = mfma16(av, b1, a1);
    }
    const float bi0 = Wgb[c0], bi1 = Wgb[c1];
    #pragma unroll
    for (int i=0;i<4;i++){
      gb[(crow+i)*512 + c0] = bfu(sigmoidf_(a0[i] + bi0));
      gb[(crow+i)*512 + c1] = bfu(sigmoidf_(a1[i] + bi1));
    }
  }
  __syncthreads();

  #pragma unroll
  for (int i=0;i<4;i++){
    const int c = tid + i*512;
    const int r = c >> 6, k0 = (c & 63)*8;
    const int kd = k0 ^ ((r&7)<<3);
    uint4 uc = *(const uint4*)(ccb + r*512 + kd);
    uint4 ug = *(const uint4*)(gb  + r*512 + k0);
    uint4 o;
    o.x = pack2(ubf_lo(uc.x)*ubf_lo(ug.x), ubf_hi(uc.x)*ubf_hi(ug.x));
    o.y = pack2(ubf_lo(uc.y)*ubf_lo(ug.y), ubf_hi(uc.y)*ubf_hi(ug.y));
    o.z = pack2(ubf_lo(uc.z)*ubf_lo(ug.z), ubf_hi(uc.z)*ubf_hi(ug.z));
    o.w = pack2(ubf_lo(uc.w)*ubf_lo(ug.w), ubf_hi(uc.w)*ubf_hi(ug.w));
    *(uint4*)(ccb + r*512 + kd) = o;
  }
  __syncthreads();

  const int t = r0 >> 6, b0r = r0 & 63;
  const long rbf = (long)r0 + rw;
  const long rbr = (long)(1023 - t)*64 + b0r + rw;
  u16* stg = gb + wv*512;

  for (int p2=0; p2<6; p2++){
    const int nt = nq*12 + p2*2;
    const int j0 = nt * 16;
    const bool isf = (j0 < 384);
    const u16* wb = isf ? wfb16 : wrb16;
    const float* bi = isf ? bihf : bihr;
    const int jb = isf ? j0 : (j0 - 384);
    const long rbase = isf ? rbf : rbr;
    u16* GIo = isf ? GIf : GIr;
    const int c0 = jb + (l & 15), c1 = c0 + 16;
    const u16* b0p = wb + (long)c0*512 + kgrp;
    const u16* b1p = wb + (long)c1*512 + kgrp;
    f32x4 a0 = {0.f,0.f,0.f,0.f}, a1 = {0.f,0.f,0.f,0.f};
    #pragma unroll
    for (int kk=0; kk<16; kk++){
      const bf16x8 av = *(const bf16x8*)(abase + ((kk*32 + kgrp) ^ swz));
      const bf16x8 b0 = *(const bf16x8*)(b0p + kk*32);
      const bf16x8 b1 = *(const bf16x8*)(b1p + kk*32);
      a0 = mfma16(av, b0, a0);
      a1 = mfma16(av, b1, a1);
    }
    const float bi0 = bi[c0], bi1 = bi[c1];
    #pragma unroll
    for (int i=0;i<4;i++){
      stg[((l>>4)*4+i)*16 + (l&15)]       = bfu(a0[i] + bi0);
      stg[256 + ((l>>4)*4+i)*16 + (l&15)] = bfu(a1[i] + bi1);
    }
    {
      const int rr = l >> 2, q = l & 3;
      const uint2 v0 = *(const uint2*)(stg + rr*16 + q*4);
      const uint2 v1 = *(const uint2*)(stg + 256 + rr*16 + q*4);
      *(uint2*)(GIo + (rbase + rr)*384 + jb      + q*4) = v0;
      *(uint2*)(GIo + (rbase + rr)*384 + jb + 16 + q*4) = v1;
    }
  }
}

// ---------------------------------------------------------------------------
// K4: GRU recurrences. 128 blocks = (dir, b), 512 threads (8 waves).
// Partials combined via shfl_xor (no LDS); hsh double-buffered ->
// ONE barrier per step. Lane layout: seg = l>>4, jj = w*16 + (l&15).
// ---------------------------------------------------------------------------
__global__ __launch_bounds__(512,2) void k_gru(
      const u16* __restrict__ GIf, const u16* __restrict__ GIr,
      const float* __restrict__ whhf, const float* __restrict__ bhhf,
      const float* __restrict__ whhr, const float* __restrict__ bhhr,
      const float* __restrict__ h0f, const float* __restrict__ h0r,
      float* __restrict__ out){
  const int d = blockIdx.x >> 6, b = blockIdx.x & 63;
  const u16* GI = d ? GIr  : GIf;
  const float* whh = d ? whhr : whhf;
  const float* bhh = d ? bhhr : bhhf;
  const float* h0  = d ? h0r  : h0f;
  const int tid = threadIdx.x;
  const int w = tid >> 6, l = tid & 63;
  const int seg = l >> 4, jj = w*16 + (l & 15);
  const bool own = (seg == 0);
  __shared__ __align__(16) float hsh[2][128];

  float4 wR[8], wZ[8], wN[8];
  {
    const float4* r0p = (const float4*)(whh + (long)(jj      )*128 + seg*32);
    const float4* r1p = (const float4*)(whh + (long)(jj + 128)*128 + seg*32);
    const float4* r2p = (const float4*)(whh + (long)(jj + 256)*128 + seg*32);
    #pragma unroll
    for (int q=0;q<8;q++){ wR[q]=r0p[q]; wZ[q]=r1p[q]; wN[q]=r2p[q]; }
  }
  float bjr=0.f, bjz=0.f, bjn=0.f, hold=0.f;
  float gr_n=0.f, gz_n=0.f, gn_n=0.f;
  if (own){
    hold = h0[b*128 + jj];
    hsh[0][jj] = hold;
    bjr = bhh[jj]; bjz = bhh[jj+128]; bjn = bhh[jj+256];
    gr_n = ubf(GI[(long)b*384 + jj]);
    gz_n = ubf(GI[(long)b*384 + jj + 128]);
    gn_n = ubf(GI[(long)b*384 + jj + 256]);
  }
  __syncthreads();

  int cur = 0;
  for (int t=0; t<1024; t++){
    float aR=0.f, aZ=0.f, aN=0.f;
    {
      const float4* hseg = (const float4*)(&hsh[cur][seg*32]);
      #pragma unroll
      for (int q=0;q<8;q++){
        const float4 hv = hseg[q];
        aR += wR[q].x*hv.x + wR[q].y*hv.y + wR[q].z*hv.z + wR[q].w*hv.w;
        aZ += wZ[q].x*hv.x + wZ[q].y*hv.y + wZ[q].z*hv.z + wZ[q].w*hv.w;
        aN += wN[q].x*hv.x + wN[q].y*hv.y + wN[q].z*hv.z + wN[q].w*hv.w;
      }
    }
    aR += __shfl_xor(aR, 16); aR += __shfl_xor(aR, 32);
    aZ += __shfl_xor(aZ, 16); aZ += __shfl_xor(aZ, 32);
    aN += __shfl_xor(aN, 16); aN += __shfl_xor(aN, 32);
    if (own){
      const float gr = gr_n, gz = gz_n, gn = gn_n;
      if (t < 1023){
        const long base = ((long)(t+1)*64 + b)*384 + jj;
        gr_n = ubf(GI[base]); gz_n = ubf(GI[base+128]); gn_n = ubf(GI[base+256]);
      }
      const float r = sigmoidf_(gr + bjr + aR);
      const float z = sigmoidf_(gz + bjz + aZ);
      const float n = tanhf_fast(gn + r*(bjn + aN));
      const float hnew = (1.f - z)*n + z*hold;
      hold = hnew;
      hsh[cur^1][jj] = hnew;
      out[((long)t*64 + b)*256 + d*128 + jj] = hnew;
    }
    __syncthreads();
    cur ^= 1;
  }
}

__global__ void k_sentinel(float* out){ out[0] = 1.0e6f; }

// ---------------------------------------------------------------------------
extern "C" void kernel_launch(void* const* d_in, const int* in_sizes, int n_in,
                              void* d_out, int out_size, void* d_ws, size_t ws_size,
                              hipStream_t stream){
  const float* passEnc = (const float*)d_in[0];
  const float* Wp_w  = (const float*)d_in[1];
  const float* Wp_b  = (const float*)d_in[2];
  const float* Wph_w = (const float*)d_in[3];
  const float* Wph_b = (const float*)d_in[4];
  const float* Wg_w  = (const float*)d_in[5];
  const float* Wg_b  = (const float*)d_in[6];
  const float* Vt    = (const float*)d_in[7];
  const float* wih_f = (const float*)d_in[8];
  const float* whh_f = (const float*)d_in[9];
  const float* bih_f = (const float*)d_in[10];
  const float* bhh_f = (const float*)d_in[11];
  const float* wih_r = (const float*)d_in[12];
  const float* whh_r = (const float*)d_in[13];
  const float* bih_r = (const float*)d_in[14];
  const float* bhh_r = (const float*)d_in[15];
  const float* h0f   = (const float*)d_in[16];
  const float* h0r   = (const float*)d_in[17];
  float* out = (float*)d_out;

  // Workspace (128 MiB): GIf bf16 | GIr bf16 | C bf16; E/F f32 overlay GIf/GIr.
  // bf16 weights (1.31 MB) in front of d_out (fully overwritten by k_gru).
  const size_t NEED = 134217728ull;
  if (ws_size < NEED){ k_sentinel<<<1,1,0,stream>>>(out); return; }
  char* base = (char*)d_ws;
  u16* GIf = (u16*)base;
  u16* GIr = (u16*)(base + 50331648ull);
  u16* C   = (u16*)(base + 100663296ull);
  float* E = (float*)base;
  float* F = (float*)(base + 33554432ull);
  u16* wgb16 = (u16*)d_out;
  u16* wfb16 = wgb16 + 262144;
  u16* wrb16 = wfb16 + 196608;

  k_cvtw <<<640,  256, 0, stream>>>(Wg_w, wih_f, wih_r, wgb16);
  k_proj <<<4096, 256, 0, stream>>>(passEnc, Wp_w, Wp_b, Wph_w, Wph_b, E, F);
  k_attn <<<1024, 512, 0, stream>>>(passEnc, E, F, Vt, C);
  k_gates<<<2048, 512, 0, stream>>>(passEnc, C, wgb16, Wg_b,
                                    wfb16, bih_f, wrb16, bih_r, GIf, GIr);
  k_gru  <<<128,  512, 0, stream>>>(GIf, GIr, whh_f, bhh_f, whh_r, bhh_r, h0f, h0r, out);
}

// Round 12
// 2739.392 us; speedup vs baseline: 1.1256x; 1.1256x over previous
//
#include <hip/hip_runtime.h>
#include <hip/hip_bf16.h>

#define DEV __device__ __forceinline__
typedef unsigned short u16;
typedef short bf16x8 __attribute__((ext_vector_type(8)));
typedef float f32x4  __attribute__((ext_vector_type(4)));

static constexpr float LOG2E = 1.44269504088896340736f;
static constexpr float C2E   = 2.88539008177792681472f; // 2*log2(e)

DEV float rcpf_(float x){ return __builtin_amdgcn_rcpf(x); }
DEV float exp2f_(float x){ return __builtin_amdgcn_exp2f(x); }
DEV float sigmoidf_(float x){ return rcpf_(1.f + exp2f_(-LOG2E*x)); }
DEV float tanhf_fast(float x){ return 1.f - 2.f*rcpf_(exp2f_(C2E*x) + 1.f); }
DEV u16 bfu(float f){
  __hip_bfloat16 h = __float2bfloat16(f);
  union { __hip_bfloat16 h; u16 u; } c; c.h = h; return c.u;
}
DEV float ubf_lo(unsigned u){ return __uint_as_float(u << 16); }
DEV float ubf_hi(unsigned u){ return __uint_as_float(u & 0xffff0000u); }
DEV unsigned pack2(float a, float b){ return (unsigned)bfu(a) | ((unsigned)bfu(b) << 16); }
DEV float ubf(u16 u){ return __uint_as_float(((unsigned)u) << 16); }

// 4-way batched reciprocal accumulate: s += sum_i v[i] / (f[i]*e[i]+1)
DEV void acc4inv(const float4 f, const float4 e, const float4 v, float& s){
  const float dx = __builtin_fmaf(f.x, e.x, 1.f);
  const float dy = __builtin_fmaf(f.y, e.y, 1.f);
  const float dz = __builtin_fmaf(f.z, e.z, 1.f);
  const float dw = __builtin_fmaf(f.w, e.w, 1.f);
  const float p2 = dx*dy, p3 = p2*dz, p4 = p3*dw;
  const float r4 = rcpf_(p4);
  const float iw = r4*p3;
  const float s3 = r4*dw;
  const float iz = s3*p2;
  const float s2 = s3*dz;
  const float iy = s2*dx;
  const float ix = s2*dy;
  s += v.x*ix; s += v.y*iy; s += v.z*iz; s += v.w*iw;
}

// ---------------------------------------------------------------------------
// K0: convert Wg (512x512), wih_f (384x512), wih_r (384x512) f32 -> bf16.
// ---------------------------------------------------------------------------
__global__ __launch_bounds__(256) void k_cvtw(const float* __restrict__ Wg,
      const float* __restrict__ wf, const float* __restrict__ wr,
      u16* __restrict__ out){
  const int i = (blockIdx.x*256 + threadIdx.x)*4;
  const float* src;
  int off;
  if (i < 262144){ src = Wg; off = i; }
  else if (i < 458752){ src = wf; off = i - 262144; }
  else { src = wr; off = i - 458752; }
  const float4 v = *(const float4*)(src + off);
  uint2 o; o.x = pack2(v.x, v.y); o.y = pack2(v.z, v.w);
  *(uint2*)(out + i) = o;
}

// ---------------------------------------------------------------------------
// K1 (R8 structure): out[r*128+h] = exp(2*(pe[r,:]·W[h,:] + b[h])).
// 1 h-col x 16 rows per thread (weight loads amortized over 16 rows).
// ---------------------------------------------------------------------------
__global__ __launch_bounds__(256,4) void k_proj(const float* __restrict__ pe,
      const float* __restrict__ Wp, const float* __restrict__ Wpb,
      const float* __restrict__ Wph, const float* __restrict__ Wphb,
      float* __restrict__ E, float* __restrict__ F){
  __shared__ __align__(16) float xs[32*256];
  const int tid = threadIdx.x;
  const int sel = blockIdx.x >> 11;
  const long r0 = (long)(blockIdx.x & 2047) * 32;
  const float* W   = sel ? Wph  : Wp;
  const float* bia = sel ? Wphb : Wpb;
  float* out       = sel ? F    : E;
  const float4* src = (const float4*)(pe + r0*256);
  float4* dst = (float4*)xs;
  #pragma unroll
  for (int i=0;i<8;i++) dst[tid + 256*i] = src[tid + 256*i];
  __syncthreads();
  const int h = tid & 127, g = tid >> 7;
  float acc[16];
  #pragma unroll
  for (int r=0;r<16;r++) acc[r] = 0.f;
  for (int kc=0; kc<8; kc++){
    float4 w4[8];
    const float4* wp = (const float4*)(W + h*256 + kc*32);
    #pragma unroll
    for (int q=0;q<8;q++) w4[q] = wp[q];
    #pragma unroll
    for (int r=0;r<16;r++){
      const float4* xr = (const float4*)(xs + (g*16+r)*256 + kc*32);
      #pragma unroll
      for (int q=0;q<8;q++){
        const float4 xv = xr[q];
        acc[r] += xv.x*w4[q].x + xv.y*w4[q].y + xv.z*w4[q].z + xv.w*w4[q].w;
      }
    }
  }
  const float bh = bia[h];
  #pragma unroll
  for (int r=0;r<16;r++)
    out[(r0 + g*16 + r)*128 + h] = exp2f_(C2E*(acc[r] + bh));
}

// ---------------------------------------------------------------------------
// K2: fused attention. Block = (b, 64-t tile), 512 threads (8 waves).
// Phase S: lane covers 4t x 4l x 32h; h-partials combined fully in-register
// (shfl_xor 16 then 32); lanes hg==0 write the S region. Phase C via MFMA.
// ---------------------------------------------------------------------------
#define AF_F    0        // [64][132] f32  (reused as Cb u16[64][264] at end)
#define AF_E    8448     // [32][132] f32
#define AF_PEt  12672    // u16[256][40] transposed PE tile (5120 f32 slots)
#define AF_S    17792    // [64][33] f32  (P u16[64][40] overlays this region)
#define AF_V    19904    // [128]
#define AF_M    20032    // [64]
#define AF_SU   20096    // [64]
#define AF_R    20160    // [64]
#define A_LDSF  20224    // 80896 bytes -> 2 blocks/CU

DEV f32x4 mfma16(bf16x8 a, bf16x8 b, f32x4 c){
  return __builtin_amdgcn_mfma_f32_16x16x32_bf16(a, b, c, 0, 0, 0);
}

__global__ __launch_bounds__(512,4) void k_attn(const float* __restrict__ pe,
      const float* __restrict__ E, const float* __restrict__ F,
      const float* __restrict__ Vt, u16* __restrict__ Cout){
  __shared__ __align__(16) float lds[A_LDSF];
  const int tid = threadIdx.x;
  const int p = blockIdx.x;
  const int b = ((p >> 7) << 3) | (p & 7);   // XCD swizzle: same-b co-located
  const int tt = (p >> 3) & 15;
  const int t0 = tt * 64;
  u16* PEtu = (u16*)(lds + AF_PEt);
  u16* Pu   = (u16*)(lds + AF_S);

  // stage F tile [64][132], v' = -2v, init m/su
  for (int i = tid; i < 64*32; i += 512){
    const int r = i >> 5, c = i & 31;
    *(float4*)(lds + AF_F + r*132 + c*4) =
      *(const float4*)(F + ((long)(t0+r)*64 + b)*128 + c*4);
  }
  if (tid < 128) lds[AF_V + tid] = -2.f * Vt[b*128 + tid];
  if (tid < 64){ lds[AF_M+tid] = -__builtin_inff(); lds[AF_SU+tid] = 0.f; }

  f32x4 cacc[8];
  #pragma unroll
  for (int i=0;i<8;i++) cacc[i] = (f32x4){0.f,0.f,0.f,0.f};

  const int lane = tid & 63, w = tid >> 6;
  const int hg = lane >> 4, li = lane & 15;   // S-phase: h-group + tuple lane
  const int th = li & 1, lq = li >> 1;        // t-half, l-quad
  const int l15 = lane & 15, kg8 = (lane >> 4) * 8;  // MFMA frag mapping
  const int tq = w >> 1, dhalf = w & 1;
  const int tcol = tq*16 + l15;
  // PEt staging decomposition
  const int sdlo = tid & 7, slp = (tid >> 3) & 15, sdhi = tid >> 7;

  for (int lt=0; lt<32; lt++){
    const int l0 = lt*32;
    __syncthreads();  // prev phase-C / softmax reads done before staging
    for (int i = tid; i < 32*32; i += 512){
      const int r = i >> 5, c = i & 31;
      *(float4*)(lds + AF_E + r*132 + c*4) =
        *(const float4*)(E + ((long)(l0+r)*64 + b)*128 + c*4);
    }
    // stage PEt[d][l] bf16 (transposed, pair-packed)
    #pragma unroll
    for (int k2=0;k2<2;k2++){
      const int dseg = (sdhi + k2*4)*8 + sdlo;    // 0..63 (float4 col)
      const int ll = slp*2;
      const float4 vA = *(const float4*)(pe + ((long)(l0+ll  )*64 + b)*256 + dseg*4);
      const float4 vB = *(const float4*)(pe + ((long)(l0+ll+1)*64 + b)*256 + dseg*4);
      u16* base = PEtu + (dseg*4)*40 + ll;
      *(unsigned*)(base)        = pack2(vA.x, vB.x);
      *(unsigned*)(base + 40)   = pack2(vA.y, vB.y);
      *(unsigned*)(base + 80)   = pack2(vA.z, vB.z);
      *(unsigned*)(base + 120)  = pack2(vA.w, vB.w);
    }
    __syncthreads();
    // phase S: 4t x 4l x 32h per lane; t rows w*8+th+2i, l rows lq+8j
    {
      float s[4][4];
      #pragma unroll
      for (int i=0;i<4;i++)
        #pragma unroll
        for (int j=0;j<4;j++) s[i][j] = 0.f;
      const float* Fb = lds + AF_F + (w*8 + th)*132 + hg*32;
      const float* Eb = lds + AF_E + lq*132 + hg*32;
      const float* Vb = lds + AF_V + hg*32;
      #pragma unroll 2
      for (int hc=0; hc<8; hc++){
        const float4 vv = *(const float4*)(Vb + hc*4);
        float4 fv[4], ev[4];
        #pragma unroll
        for (int i=0;i<4;i++) fv[i] = *(const float4*)(Fb + i*264 + hc*4);
        #pragma unroll
        for (int j=0;j<4;j++) ev[j] = *(const float4*)(Eb + j*1056 + hc*4);
        #pragma unroll
        for (int i=0;i<4;i++){
          #pragma unroll
          for (int j=0;j<4;j++)
            acc4inv(fv[i], ev[j], vv, s[i][j]);
        }
      }
      // combine the 4 h-group partials fully in-register
      #pragma unroll
      for (int i=0;i<4;i++)
        #pragma unroll
        for (int j=0;j<4;j++){
          s[i][j] += __shfl_xor(s[i][j], 16);
          s[i][j] += __shfl_xor(s[i][j], 32);
        }
      if (hg == 0){
        #pragma unroll
        for (int i=0;i<4;i++)
          #pragma unroll
          for (int j=0;j<4;j++)
            lds[AF_S + (w*8 + th + 2*i)*33 + (lq + 8*j)] = s[i][j];
      }
    }
    __syncthreads();
    // online softmax; P written bf16 over the S region (barrier between)
    {
      const int t = tid >> 3, sub = tid & 7;
      const float* Srow = lds + AF_S + t*33 + sub*4;
      const float s0=Srow[0], s1=Srow[1], s2=Srow[2], s3=Srow[3];
      float mx = fmaxf(fmaxf(s0,s1), fmaxf(s2,s3));
      #pragma unroll
      for (int off=1; off<8; off<<=1) mx = fmaxf(mx, __shfl_xor(mx, off));
      const float m_old = lds[AF_M + t];
      const float m_new = fmaxf(m_old, mx);
      const float p0 = exp2f_(LOG2E*(s0-m_new));
      const float p1 = exp2f_(LOG2E*(s1-m_new));
      const float p2 = exp2f_(LOG2E*(s2-m_new));
      const float p3 = exp2f_(LOG2E*(s3-m_new));
      float ps = p0+p1+p2+p3;
      #pragma unroll
      for (int off=1; off<8; off<<=1) ps += __shfl_xor(ps, off);
      __syncthreads();   // all S reads done before P overwrites the region
      uint2 pw; pw.x = pack2(p0,p1); pw.y = pack2(p2,p3);
      *(uint2*)(Pu + t*40 + sub*4) = pw;
      if (sub==0){
        const float rsc = exp2f_(LOG2E*(m_old - m_new));
        lds[AF_R + t] = rsc;
        lds[AF_SU + t] = lds[AF_SU + t]*rsc + ps;
        lds[AF_M + t] = m_new;
      }
    }
    __syncthreads();
    // phase C (MFMA): rescale acc, then D[d][t] += PEt · P^T
    {
      const float rs = lds[AF_R + tcol];
      #pragma unroll
      for (int p2=0;p2<8;p2++){
        cacc[p2][0]*=rs; cacc[p2][1]*=rs; cacc[p2][2]*=rs; cacc[p2][3]*=rs;
      }
      const bf16x8 bfrag = *(const bf16x8*)(Pu + tcol*40 + kg8);
      #pragma unroll
      for (int p2=0;p2<8;p2++){
        const int dt = dhalf*8 + p2;
        const bf16x8 afrag = *(const bf16x8*)(PEtu + (dt*16 + l15)*40 + kg8);
        cacc[p2] = mfma16(afrag, bfrag, cacc[p2]);
      }
    }
  }
  // epilogue: normalize, bounce C^T through LDS (F region), coalesced store
  __syncthreads();
  {
    const float inv = rcpf_(lds[AF_SU + tcol]);
    u16* Cb = (u16*)(lds + AF_F);   // [64][264]
    const int rb = (lane >> 4) * 4;
    #pragma unroll
    for (int p2=0;p2<8;p2++){
      const int dd = (dhalf*8 + p2)*16 + rb;
      *(unsigned*)(Cb + tcol*264 + dd)     = pack2(cacc[p2][0]*inv, cacc[p2][1]*inv);
      *(unsigned*)(Cb + tcol*264 + dd + 2) = pack2(cacc[p2][2]*inv, cacc[p2][3]*inv);
    }
  }
  __syncthreads();
  {
    const u16* Cb = (const u16*)(lds + AF_F);
    #pragma unroll
    for (int k2=0;k2<4;k2++){
      const int flat = tid + k2*512;
      const int t = flat >> 5, dg = flat & 31;
      const uint4 v = *(const uint4*)(Cb + t*264 + dg*8);
      *(uint4*)(Cout + ((long)(t0+t)*64 + b)*256 + dg*8) = v;
    }
  }
}

// ---------------------------------------------------------------------------
// K3: MFMA gates, 8 waves (512 thr), 32 rows/block.
// ---------------------------------------------------------------------------
__global__ __launch_bounds__(512,2) void k_gates(const float* __restrict__ pe,
      const u16* __restrict__ Cin,
      const u16* __restrict__ Wgb16, const float* __restrict__ Wgb,
      const u16* __restrict__ wfb16, const float* __restrict__ bihf,
      const u16* __restrict__ wrb16, const float* __restrict__ bihr,
      u16* __restrict__ GIf, u16* __restrict__ GIr){
  __shared__ __align__(16) u16 ccb[32*512];
  __shared__ __align__(16) u16 gb [32*512];
  const int tid = threadIdx.x;
  const int r0 = blockIdx.x * 32;

  #pragma unroll
  for (int i=0;i<4;i++){
    const int c = tid + i*512;
    const int r = c >> 6, k0 = (c & 63)*8;
    const int kd = k0 ^ ((r&7)<<3);
    uint4 o;
    if (k0 < 256){
      const float4 f0 = *(const float4*)(pe + ((long)(r0+r))*256 + k0);
      const float4 f1 = *(const float4*)(pe + ((long)(r0+r))*256 + k0 + 4);
      o.x = pack2(f0.x,f0.y); o.y = pack2(f0.z,f0.w);
      o.z = pack2(f1.x,f1.y); o.w = pack2(f1.z,f1.w);
    } else {
      o = *(const uint4*)(Cin + ((long)(r0+r))*256 + (k0-256));
    }
    *(uint4*)(ccb + r*512 + kd) = o;
  }
  __syncthreads();

  const int l = tid & 63, wv = tid >> 6;   // 8 waves
  const int rw = (wv >> 2) * 16;           // row half
  const int nq = wv & 3;                   // col quarter
  const int arow = rw + (l & 15);
  const int kgrp = (l >> 4) * 8;
  const int swz  = (l & 7) << 3;
  const u16* abase = ccb + arow*512;
  const int crow = rw + (l >> 4) * 4;

  for (int p2=0; p2<4; p2++){
    const int n0 = nq*128 + p2*32;
    const int c0 = n0 + (l & 15), c1 = c0 + 16;
    const u16* b0p = Wgb16 + (long)c0*512 + kgrp;
    const u16* b1p = Wgb16 + (long)c1*512 + kgrp;
    f32x4 a0 = {0.f,0.f,0.f,0.f}, a1 = {0.f,0.f,0.f,0.f};
    #pragma unroll
    for (int kk=0; kk<16; kk++){
      const bf16x8 av = *(const bf16x8*)(abase + ((kk*32 + kgrp) ^ swz));
      const bf16x8 b0 = *(const bf16x8*)(b0p + kk*32);
      const bf16x8 b1 = *(const bf16x8*)(b1p + kk*32);
      a0 = mfma16(av, b0, a0);
      a1 = mfma16(av, b1, a1);
    }
    const float bi0 = Wgb[c0], bi1 = Wgb[c1];
    #pragma unroll
    for (int i=0;i<4;i++){
      gb[(crow+i)*512 + c0] = bfu(sigmoidf_(a0[i] + bi0));
      gb[(crow+i)*512 + c1] = bfu(sigmoidf_(a1[i] + bi1));
    }
  }
  __syncthreads();

  #pragma unroll
  for (int i=0;i<4;i++){
    const int c = tid + i*512;
    const int r = c >> 6, k0 = (c & 63)*8;
    const int kd = k0 ^ ((r&7)<<3);
    uint4 uc = *(const uint4*)(ccb + r*512 + kd);
    uint4 ug = *(const uint4*)(gb  + r*512 + k0);
    uint4 o;
    o.x = pack2(ubf_lo(uc.x)*ubf_lo(ug.x), ubf_hi(uc.x)*ubf_hi(ug.x));
    o.y = pack2(ubf_lo(uc.y)*ubf_lo(ug.y), ubf_hi(uc.y)*ubf_hi(ug.y));
    o.z = pack2(ubf_lo(uc.z)*ubf_lo(ug.z), ubf_hi(uc.z)*ubf_hi(ug.z));
    o.w = pack2(ubf_lo(uc.w)*ubf_lo(ug.w), ubf_hi(uc.w)*ubf_hi(ug.w));
    *(uint4*)(ccb + r*512 + kd) = o;
  }
  __syncthreads();

  const int t = r0 >> 6, b0r = r0 & 63;
  const long rbf = (long)r0 + rw;
  const long rbr = (long)(1023 - t)*64 + b0r + rw;
  u16* stg = gb + wv*512;

  for (int p2=0; p2<6; p2++){
    const int nt = nq*12 + p2*2;
    const int j0 = nt * 16;
    const bool isf = (j0 < 384);
    const u16* wb = isf ? wfb16 : wrb16;
    const float* bi = isf ? bihf : bihr;
    const int jb = isf ? j0 : (j0 - 384);
    const long rbase = isf ? rbf : rbr;
    u16* GIo = isf ? GIf : GIr;
    const int c0 = jb + (l & 15), c1 = c0 + 16;
    const u16* b0p = wb + (long)c0*512 + kgrp;
    const u16* b1p = wb + (long)c1*512 + kgrp;
    f32x4 a0 = {0.f,0.f,0.f,0.f}, a1 = {0.f,0.f,0.f,0.f};
    #pragma unroll
    for (int kk=0; kk<16; kk++){
      const bf16x8 av = *(const bf16x8*)(abase + ((kk*32 + kgrp) ^ swz));
      const bf16x8 b0 = *(const bf16x8*)(b0p + kk*32);
      const bf16x8 b1 = *(const bf16x8*)(b1p + kk*32);
      a0 = mfma16(av, b0, a0);
      a1 = mfma16(av, b1, a1);
    }
    const float bi0 = bi[c0], bi1 = bi[c1];
    #pragma unroll
    for (int i=0;i<4;i++){
      stg[((l>>4)*4+i)*16 + (l&15)]       = bfu(a0[i] + bi0);
      stg[256 + ((l>>4)*4+i)*16 + (l&15)] = bfu(a1[i] + bi1);
    }
    {
      const int rr = l >> 2, q = l & 3;
      const uint2 v0 = *(const uint2*)(stg + rr*16 + q*4);
      const uint2 v1 = *(const uint2*)(stg + 256 + rr*16 + q*4);
      *(uint2*)(GIo + (rbase + rr)*384 + jb      + q*4) = v0;
      *(uint2*)(GIo + (rbase + rr)*384 + jb + 16 + q*4) = v1;
    }
  }
}

// ---------------------------------------------------------------------------
// K4 (R8 structure + depth-2 GI prefetch): GRU recurrences.
// 128 blocks = (dir, b), 512 threads; seg-split partial dots via LDS;
// GI loads issued 2 steps ahead to cover HBM latency.
// ---------------------------------------------------------------------------
__global__ __launch_bounds__(512,2) void k_gru(
      const u16* __restrict__ GIf, const u16* __restrict__ GIr,
      const float* __restrict__ whhf, const float* __restrict__ bhhf,
      const float* __restrict__ whhr, const float* __restrict__ bhhr,
      const float* __restrict__ h0f, const float* __restrict__ h0r,
      float* __restrict__ out){
  const int d = blockIdx.x >> 6, b = blockIdx.x & 63;
  const u16* GI = d ? GIr  : GIf;
  const float* whh = d ? whhr : whhf;
  const float* bhh = d ? bhhr : bhhf;
  const float* h0  = d ? h0r  : h0f;
  const int tid = threadIdx.x;
  const int seg = tid >> 7, j0 = tid & 127;
  __shared__ __align__(16) float hsh[128];
  __shared__ __align__(16) float part[4*384];

  float4 wR[8], wZ[8], wN[8];
  {
    const float4* r0p = (const float4*)(whh + (long)(j0      )*128 + seg*32);
    const float4* r1p = (const float4*)(whh + (long)(j0 + 128)*128 + seg*32);
    const float4* r2p = (const float4*)(whh + (long)(j0 + 256)*128 + seg*32);
    #pragma unroll
    for (int q=0;q<8;q++){ wR[q]=r0p[q]; wZ[q]=r1p[q]; wN[q]=r2p[q]; }
  }
  float bjr=0.f, bjz=0.f, bjn=0.f, hold=0.f;
  float grc=0.f, gzc=0.f, gnc=0.f;   // step t
  float grn=0.f, gzn=0.f, gnn=0.f;   // step t+1
  if (tid < 128){
    hsh[tid] = hold = h0[b*128 + tid];
    bjr = bhh[tid]; bjz = bhh[tid+128]; bjn = bhh[tid+256];
    const long b0 = (long)b*384 + tid;
    grc = ubf(GI[b0]); gzc = ubf(GI[b0+128]); gnc = ubf(GI[b0+256]);
    const long b1 = ((long)64 + b)*384 + tid;
    grn = ubf(GI[b1]); gzn = ubf(GI[b1+128]); gnn = ubf(GI[b1+256]);
  }
  __syncthreads();

  for (int t=0; t<1024; t++){
    {
      float aR=0.f, aZ=0.f, aN=0.f;
      const float4* hseg = (const float4*)(hsh + seg*32);
      #pragma unroll
      for (int q=0;q<8;q++){
        const float4 hv = hseg[q];
        aR += wR[q].x*hv.x + wR[q].y*hv.y + wR[q].z*hv.z + wR[q].w*hv.w;
        aZ += wZ[q].x*hv.x + wZ[q].y*hv.y + wZ[q].z*hv.z + wZ[q].w*hv.w;
        aN += wN[q].x*hv.x + wN[q].y*hv.y + wN[q].z*hv.z + wN[q].w*hv.w;
      }
      part[seg*384 + j0]       = aR;
      part[seg*384 + j0 + 128] = aZ;
      part[seg*384 + j0 + 256] = aN;
    }
    __syncthreads();
    if (tid < 128){
      const float gr = grc, gz = gzc, gn = gnc;
      grc = grn; gzc = gzn; gnc = gnn;
      if (t < 1022){
        const long base = ((long)(t+2)*64 + b)*384 + tid;
        grn = ubf(GI[base]); gzn = ubf(GI[base+128]); gnn = ubf(GI[base+256]);
      }
      const float ghr = bjr + ((part[tid]       + part[384+tid])       + (part[768+tid]       + part[1152+tid]));
      const float ghz = bjz + ((part[tid+128]   + part[384+tid+128])   + (part[768+tid+128]   + part[1152+tid+128]));
      const float ghn = bjn + ((part[tid+256]   + part[384+tid+256])   + (part[768+tid+256]   + part[1152+tid+256]));
      const float r = sigmoidf_(gr + ghr);
      const float z = sigmoidf_(gz + ghz);
      const float n = tanhf_fast(gn + r*ghn);
      const float hnew = (1.f - z)*n + z*hold;
      hold = hnew;
      hsh[tid] = hnew;
      out[((long)t*64 + b)*256 + d*128 + tid] = hnew;
    }
    __syncthreads();
  }
}

__global__ void k_sentinel(float* out){ out[0] = 1.0e6f; }

// ---------------------------------------------------------------------------
extern "C" void kernel_launch(void* const* d_in, const int* in_sizes, int n_in,
                              void* d_out, int out_size, void* d_ws, size_t ws_size,
                              hipStream_t stream){
  const float* passEnc = (const float*)d_in[0];
  const float* Wp_w  = (const float*)d_in[1];
  const float* Wp_b  = (const float*)d_in[2];
  const float* Wph_w = (const float*)d_in[3];
  const float* Wph_b = (const float*)d_in[4];
  const float* Wg_w  = (const float*)d_in[5];
  const float* Wg_b  = (const float*)d_in[6];
  const float* Vt    = (const float*)d_in[7];
  const float* wih_f = (const float*)d_in[8];
  const float* whh_f = (const float*)d_in[9];
  const float* bih_f = (const float*)d_in[10];
  const float* bhh_f = (const float*)d_in[11];
  const float* wih_r = (const float*)d_in[12];
  const float* whh_r = (const float*)d_in[13];
  const float* bih_r = (const float*)d_in[14];
  const float* bhh_r = (const float*)d_in[15];
  const float* h0f   = (const float*)d_in[16];
  const float* h0r   = (const float*)d_in[17];
  float* out = (float*)d_out;

  // Workspace (128 MiB): GIf bf16 | GIr bf16 | C bf16; E/F f32 overlay GIf/GIr.
  // bf16 weights (1.31 MB) in front of d_out (fully overwritten by k_gru).
  const size_t NEED = 134217728ull;
  if (ws_size < NEED){ k_sentinel<<<1,1,0,stream>>>(out); return; }
  char* base = (char*)d_ws;
  u16* GIf = (u16*)base;
  u16* GIr = (u16*)(base + 50331648ull);
  u16* C   = (u16*)(base + 100663296ull);
  float* E = (float*)base;
  float* F = (float*)(base + 33554432ull);
  u16* wgb16 = (u16*)d_out;
  u16* wfb16 = wgb16 + 262144;
  u16* wrb16 = wfb16 + 196608;

  k_cvtw <<<640,  256, 0, stream>>>(Wg_w, wih_f, wih_r, wgb16);
  k_proj <<<4096, 256, 0, stream>>>(passEnc, Wp_w, Wp_b, Wph_w, Wph_b, E, F);
  k_attn <<<1024, 512, 0, stream>>>(passEnc, E, F, Vt, C);
  k_gates<<<2048, 512, 0, stream>>>(passEnc, C, wgb16, Wg_b,
                                    wfb16, bih_f, wrb16, bih_r, GIf, GIr);
  k_gru  <<<128,  512, 0, stream>>>(GIf, GIr, whh_f, bhh_f, whh_r, bhh_r, h0f, h0r, out);
}

// Round 13
// 2116.615 us; speedup vs baseline: 1.4568x; 1.2942x over previous
//
#include <hip/hip_runtime.h>
#include <hip/hip_bf16.h>

#define DEV __device__ __forceinline__
typedef unsigned short u16;
typedef short bf16x8 __attribute__((ext_vector_type(8)));
typedef float f32x4  __attribute__((ext_vector_type(4)));

static constexpr float LOG2E = 1.44269504088896340736f;
static constexpr float C2E   = 2.88539008177792681472f; // 2*log2(e)

DEV float rcpf_(float x){ return __builtin_amdgcn_rcpf(x); }
DEV float exp2f_(float x){ return __builtin_amdgcn_exp2f(x); }
DEV float sigmoidf_(float x){ return rcpf_(1.f + exp2f_(-LOG2E*x)); }
DEV float tanhf_fast(float x){ return 1.f - 2.f*rcpf_(exp2f_(C2E*x) + 1.f); }
DEV u16 bfu(float f){
  __hip_bfloat16 h = __float2bfloat16(f);
  union { __hip_bfloat16 h; u16 u; } c; c.h = h; return c.u;
}
DEV float ubf_lo(unsigned u){ return __uint_as_float(u << 16); }
DEV float ubf_hi(unsigned u){ return __uint_as_float(u & 0xffff0000u); }
DEV unsigned pack2(float a, float b){ return (unsigned)bfu(a) | ((unsigned)bfu(b) << 16); }
DEV float ubf(u16 u){ return __uint_as_float(((unsigned)u) << 16); }

// 4-way batched reciprocal accumulate: s += sum_i v[i] / (f[i]*e[i]+1)
DEV void acc4inv(const float4 f, const float4 e, const float4 v, float& s){
  const float dx = __builtin_fmaf(f.x, e.x, 1.f);
  const float dy = __builtin_fmaf(f.y, e.y, 1.f);
  const float dz = __builtin_fmaf(f.z, e.z, 1.f);
  const float dw = __builtin_fmaf(f.w, e.w, 1.f);
  const float p2 = dx*dy, p3 = p2*dz, p4 = p3*dw;
  const float r4 = rcpf_(p4);
  const float iw = r4*p3;
  const float s3 = r4*dw;
  const float iz = s3*p2;
  const float s2 = s3*dz;
  const float iy = s2*dx;
  const float ix = s2*dy;
  s += v.x*ix; s += v.y*iy; s += v.z*iz; s += v.w*iw;
}

// ---------------------------------------------------------------------------
// K0: prep. blocks [0,320): pack Wg/wih_f/wih_r (f32) into bf16 MFMA B-frag
// order P[((cb*16+kk)*64+l)*8+j] = W[cb*16+(l&15)][kk*32+(l>>4)*8+j].
// blocks [320,448): WpT[k*128+h] = Wp[h*256+k]; [448,576): WphT likewise.
// ---------------------------------------------------------------------------
__global__ __launch_bounds__(256) void k_prep(const float* __restrict__ Wg,
      const float* __restrict__ wf, const float* __restrict__ wr,
      const float* __restrict__ Wp, const float* __restrict__ Wph,
      u16* __restrict__ wgbP, u16* __restrict__ wfbP, u16* __restrict__ wrbP,
      float* __restrict__ WpT, float* __restrict__ WphT){
  const int blk = blockIdx.x, tid = threadIdx.x;
  if (blk < 320){
    const int gid = blk*256 + tid;      // [0, 81920)
    const float* src; u16* dst; int local;
    if (gid < 32768){ src = Wg; dst = wgbP; local = gid; }
    else if (gid < 57344){ src = wf; dst = wfbP; local = gid - 32768; }
    else { src = wr; dst = wrbP; local = gid - 57344; }
    const int cb  = local >> 10;        // /(16*64)
    const int rem = local & 1023;
    const int kk = rem >> 6, l = rem & 63;
    const int row = cb*16 + (l & 15);
    const int k0  = kk*32 + (l >> 4)*8;
    const float4 f0 = *(const float4*)(src + (long)row*512 + k0);
    const float4 f1 = *(const float4*)(src + (long)row*512 + k0 + 4);
    uint4 o;
    o.x = pack2(f0.x, f0.y); o.y = pack2(f0.z, f0.w);
    o.z = pack2(f1.x, f1.y); o.w = pack2(f1.z, f1.w);
    *(uint4*)(dst + (long)local*8) = o;
  } else if (blk < 448){
    const int idx = (blk-320)*256 + tid;   // [0, 32768)
    WpT[idx] = Wp[(idx & 127)*256 + (idx >> 7)];
  } else {
    const int idx = (blk-448)*256 + tid;
    WphT[idx] = Wph[(idx & 127)*256 + (idx >> 7)];
  }
}

// ---------------------------------------------------------------------------
// K1: out[r*128+h] = exp(2*(pe[r,:]·W[h,:] + b[h])) using transposed WT[k][h]
// (coalesced 256B wave-loads). 1 h-col x 16 rows per thread.
// ---------------------------------------------------------------------------
__global__ __launch_bounds__(256,4) void k_proj(const float* __restrict__ pe,
      const float* __restrict__ WpT, const float* __restrict__ Wpb,
      const float* __restrict__ WphT, const float* __restrict__ Wphb,
      float* __restrict__ E, float* __restrict__ F){
  __shared__ __align__(16) float xs[32*256];
  const int tid = threadIdx.x;
  const int sel = blockIdx.x >> 11;
  const long r0 = (long)(blockIdx.x & 2047) * 32;
  const float* WT  = sel ? WphT : WpT;
  const float* bia = sel ? Wphb : Wpb;
  float* out       = sel ? F    : E;
  const float4* src = (const float4*)(pe + r0*256);
  float4* dst = (float4*)xs;
  #pragma unroll
  for (int i=0;i<8;i++) dst[tid + 256*i] = src[tid + 256*i];
  __syncthreads();
  const int h = tid & 127, g = tid >> 7;
  float acc[16];
  #pragma unroll
  for (int r=0;r<16;r++) acc[r] = 0.f;
  for (int kc=0; kc<8; kc++){
    float w[32];
    #pragma unroll
    for (int q=0;q<32;q++) w[q] = WT[(kc*32 + q)*128 + h];
    #pragma unroll
    for (int r=0;r<16;r++){
      const float4* xr = (const float4*)(xs + (g*16+r)*256 + kc*32);
      #pragma unroll
      for (int q=0;q<8;q++){
        const float4 xv = xr[q];
        acc[r] += xv.x*w[q*4] + xv.y*w[q*4+1] + xv.z*w[q*4+2] + xv.w*w[q*4+3];
      }
    }
  }
  const float bh = bia[h];
  #pragma unroll
  for (int r=0;r<16;r++)
    out[(r0 + g*16 + r)*128 + h] = exp2f_(C2E*(acc[r] + bh));
}

// ---------------------------------------------------------------------------
// K2: fused attention (unchanged from R12). Block = (b, 64-t tile), 512 thr.
// ---------------------------------------------------------------------------
#define AF_F    0        // [64][132] f32  (reused as Cb u16[64][264] at end)
#define AF_E    8448     // [32][132] f32
#define AF_PEt  12672    // u16[256][40] transposed PE tile (5120 f32 slots)
#define AF_S    17792    // [64][33] f32  (P u16[64][40] overlays this region)
#define AF_V    19904    // [128]
#define AF_M    20032    // [64]
#define AF_SU   20096    // [64]
#define AF_R    20160    // [64]
#define A_LDSF  20224    // 80896 bytes -> 2 blocks/CU

DEV f32x4 mfma16(bf16x8 a, bf16x8 b, f32x4 c){
  return __builtin_amdgcn_mfma_f32_16x16x32_bf16(a, b, c, 0, 0, 0);
}

__global__ __launch_bounds__(512,4) void k_attn(const float* __restrict__ pe,
      const float* __restrict__ E, const float* __restrict__ F,
      const float* __restrict__ Vt, u16* __restrict__ Cout){
  __shared__ __align__(16) float lds[A_LDSF];
  const int tid = threadIdx.x;
  const int p = blockIdx.x;
  const int b = ((p >> 7) << 3) | (p & 7);   // XCD swizzle: same-b co-located
  const int tt = (p >> 3) & 15;
  const int t0 = tt * 64;
  u16* PEtu = (u16*)(lds + AF_PEt);
  u16* Pu   = (u16*)(lds + AF_S);

  for (int i = tid; i < 64*32; i += 512){
    const int r = i >> 5, c = i & 31;
    *(float4*)(lds + AF_F + r*132 + c*4) =
      *(const float4*)(F + ((long)(t0+r)*64 + b)*128 + c*4);
  }
  if (tid < 128) lds[AF_V + tid] = -2.f * Vt[b*128 + tid];
  if (tid < 64){ lds[AF_M+tid] = -__builtin_inff(); lds[AF_SU+tid] = 0.f; }

  f32x4 cacc[8];
  #pragma unroll
  for (int i=0;i<8;i++) cacc[i] = (f32x4){0.f,0.f,0.f,0.f};

  const int lane = tid & 63, w = tid >> 6;
  const int hg = lane >> 4, li = lane & 15;
  const int th = li & 1, lq = li >> 1;
  const int l15 = lane & 15, kg8 = (lane >> 4) * 8;
  const int tq = w >> 1, dhalf = w & 1;
  const int tcol = tq*16 + l15;
  const int sdlo = tid & 7, slp = (tid >> 3) & 15, sdhi = tid >> 7;

  for (int lt=0; lt<32; lt++){
    const int l0 = lt*32;
    __syncthreads();
    for (int i = tid; i < 32*32; i += 512){
      const int r = i >> 5, c = i & 31;
      *(float4*)(lds + AF_E + r*132 + c*4) =
        *(const float4*)(E + ((long)(l0+r)*64 + b)*128 + c*4);
    }
    #pragma unroll
    for (int k2=0;k2<2;k2++){
      const int dseg = (sdhi + k2*4)*8 + sdlo;
      const int ll = slp*2;
      const float4 vA = *(const float4*)(pe + ((long)(l0+ll  )*64 + b)*256 + dseg*4);
      const float4 vB = *(const float4*)(pe + ((long)(l0+ll+1)*64 + b)*256 + dseg*4);
      u16* base = PEtu + (dseg*4)*40 + ll;
      *(unsigned*)(base)        = pack2(vA.x, vB.x);
      *(unsigned*)(base + 40)   = pack2(vA.y, vB.y);
      *(unsigned*)(base + 80)   = pack2(vA.z, vB.z);
      *(unsigned*)(base + 120)  = pack2(vA.w, vB.w);
    }
    __syncthreads();
    {
      float s[4][4];
      #pragma unroll
      for (int i=0;i<4;i++)
        #pragma unroll
        for (int j=0;j<4;j++) s[i][j] = 0.f;
      const float* Fb = lds + AF_F + (w*8 + th)*132 + hg*32;
      const float* Eb = lds + AF_E + lq*132 + hg*32;
      const float* Vb = lds + AF_V + hg*32;
      #pragma unroll 2
      for (int hc=0; hc<8; hc++){
        const float4 vv = *(const float4*)(Vb + hc*4);
        float4 fv[4], ev[4];
        #pragma unroll
        for (int i=0;i<4;i++) fv[i] = *(const float4*)(Fb + i*264 + hc*4);
        #pragma unroll
        for (int j=0;j<4;j++) ev[j] = *(const float4*)(Eb + j*1056 + hc*4);
        #pragma unroll
        for (int i=0;i<4;i++){
          #pragma unroll
          for (int j=0;j<4;j++)
            acc4inv(fv[i], ev[j], vv, s[i][j]);
        }
      }
      #pragma unroll
      for (int i=0;i<4;i++)
        #pragma unroll
        for (int j=0;j<4;j++){
          s[i][j] += __shfl_xor(s[i][j], 16);
          s[i][j] += __shfl_xor(s[i][j], 32);
        }
      if (hg == 0){
        #pragma unroll
        for (int i=0;i<4;i++)
          #pragma unroll
          for (int j=0;j<4;j++)
            lds[AF_S + (w*8 + th + 2*i)*33 + (lq + 8*j)] = s[i][j];
      }
    }
    __syncthreads();
    {
      const int t = tid >> 3, sub = tid & 7;
      const float* Srow = lds + AF_S + t*33 + sub*4;
      const float s0=Srow[0], s1=Srow[1], s2=Srow[2], s3=Srow[3];
      float mx = fmaxf(fmaxf(s0,s1), fmaxf(s2,s3));
      #pragma unroll
      for (int off=1; off<8; off<<=1) mx = fmaxf(mx, __shfl_xor(mx, off));
      const float m_old = lds[AF_M + t];
      const float m_new = fmaxf(m_old, mx);
      const float p0 = exp2f_(LOG2E*(s0-m_new));
      const float p1 = exp2f_(LOG2E*(s1-m_new));
      const float p2 = exp2f_(LOG2E*(s2-m_new));
      const float p3 = exp2f_(LOG2E*(s3-m_new));
      float ps = p0+p1+p2+p3;
      #pragma unroll
      for (int off=1; off<8; off<<=1) ps += __shfl_xor(ps, off);
      __syncthreads();
      uint2 pw; pw.x = pack2(p0,p1); pw.y = pack2(p2,p3);
      *(uint2*)(Pu + t*40 + sub*4) = pw;
      if (sub==0){
        const float rsc = exp2f_(LOG2E*(m_old - m_new));
        lds[AF_R + t] = rsc;
        lds[AF_SU + t] = lds[AF_SU + t]*rsc + ps;
        lds[AF_M + t] = m_new;
      }
    }
    __syncthreads();
    {
      const float rs = lds[AF_R + tcol];
      #pragma unroll
      for (int p2=0;p2<8;p2++){
        cacc[p2][0]*=rs; cacc[p2][1]*=rs; cacc[p2][2]*=rs; cacc[p2][3]*=rs;
      }
      const bf16x8 bfrag = *(const bf16x8*)(Pu + tcol*40 + kg8);
      #pragma unroll
      for (int p2=0;p2<8;p2++){
        const int dt = dhalf*8 + p2;
        const bf16x8 afrag = *(const bf16x8*)(PEtu + (dt*16 + l15)*40 + kg8);
        cacc[p2] = mfma16(afrag, bfrag, cacc[p2]);
      }
    }
  }
  __syncthreads();
  {
    const float inv = rcpf_(lds[AF_SU + tcol]);
    u16* Cb = (u16*)(lds + AF_F);
    const int rb = (lane >> 4) * 4;
    #pragma unroll
    for (int p2=0;p2<8;p2++){
      const int dd = (dhalf*8 + p2)*16 + rb;
      *(unsigned*)(Cb + tcol*264 + dd)     = pack2(cacc[p2][0]*inv, cacc[p2][1]*inv);
      *(unsigned*)(Cb + tcol*264 + dd + 2) = pack2(cacc[p2][2]*inv, cacc[p2][3]*inv);
    }
  }
  __syncthreads();
  {
    const u16* Cb = (const u16*)(lds + AF_F);
    #pragma unroll
    for (int k2=0;k2<4;k2++){
      const int flat = tid + k2*512;
      const int t = flat >> 5, dg = flat & 31;
      const uint4 v = *(const uint4*)(Cb + t*264 + dg*8);
      *(uint4*)(Cout + ((long)(t0+t)*64 + b)*256 + dg*8) = v;
    }
  }
}

// ---------------------------------------------------------------------------
// K3: MFMA gates, 8 waves, 32 rows/block. B-operands from PACKED weights
// (coalesced 1KB wave-loads).
// ---------------------------------------------------------------------------
__global__ __launch_bounds__(512,2) void k_gates(const float* __restrict__ pe,
      const u16* __restrict__ Cin,
      const u16* __restrict__ wgbP, const float* __restrict__ Wgb,
      const u16* __restrict__ wfbP, const float* __restrict__ bihf,
      const u16* __restrict__ wrbP, const float* __restrict__ bihr,
      u16* __restrict__ GIf, u16* __restrict__ GIr){
  __shared__ __align__(16) u16 ccb[32*512];
  __shared__ __align__(16) u16 gb [32*512];
  const int tid = threadIdx.x;
  const int r0 = blockIdx.x * 32;

  #pragma unroll
  for (int i=0;i<4;i++){
    const int c = tid + i*512;
    const int r = c >> 6, k0 = (c & 63)*8;
    const int kd = k0 ^ ((r&7)<<3);
    uint4 o;
    if (k0 < 256){
      const float4 f0 = *(const float4*)(pe + ((long)(r0+r))*256 + k0);
      const float4 f1 = *(const float4*)(pe + ((long)(r0+r))*256 + k0 + 4);
      o.x = pack2(f0.x,f0.y); o.y = pack2(f0.z,f0.w);
      o.z = pack2(f1.x,f1.y); o.w = pack2(f1.z,f1.w);
    } else {
      o = *(const uint4*)(Cin + ((long)(r0+r))*256 + (k0-256));
    }
    *(uint4*)(ccb + r*512 + kd) = o;
  }
  __syncthreads();

  const int l = tid & 63, wv = tid >> 6;   // 8 waves
  const int rw = (wv >> 2) * 16;           // row half
  const int nq = wv & 3;                   // col quarter
  const int arow = rw + (l & 15);
  const int kgrp = (l >> 4) * 8;
  const int swz  = (l & 7) << 3;
  const u16* abase = ccb + arow*512;
  const int crow = rw + (l >> 4) * 4;

  for (int p2=0; p2<4; p2++){
    const int cb0 = nq*8 + p2*2, cb1 = cb0 + 1;
    const int c0 = cb0*16 + (l & 15), c1 = c0 + 16;
    const u16* b0p = wgbP + ((long)cb0*16*64 + (long)l)*8;
    const u16* b1p = wgbP + ((long)cb1*16*64 + (long)l)*8;
    f32x4 a0 = {0.f,0.f,0.f,0.f}, a1 = {0.f,0.f,0.f,0.f};
    #pragma unroll
    for (int kk=0; kk<16; kk++){
      const bf16x8 av = *(const bf16x8*)(abase + ((kk*32 + kgrp) ^ swz));
      const bf16x8 b0 = *(const bf16x8*)(b0p + kk*512);
      const bf16x8 b1 = *(const bf16x8*)(b1p + kk*512);
      a0 = mfma16(av, b0, a0);
      a1 = mfma16(av, b1, a1);
    }
    const float bi0 = Wgb[c0], bi1 = Wgb[c1];
    #pragma unroll
    for (int i=0;i<4;i++){
      gb[(crow+i)*512 + c0] = bfu(sigmoidf_(a0[i] + bi0));
      gb[(crow+i)*512 + c1] = bfu(sigmoidf_(a1[i] + bi1));
    }
  }
  __syncthreads();

  #pragma unroll
  for (int i=0;i<4;i++){
    const int c = tid + i*512;
    const int r = c >> 6, k0 = (c & 63)*8;
    const int kd = k0 ^ ((r&7)<<3);
    uint4 uc = *(const uint4*)(ccb + r*512 + kd);
    uint4 ug = *(const uint4*)(gb  + r*512 + k0);
    uint4 o;
    o.x = pack2(ubf_lo(uc.x)*ubf_lo(ug.x), ubf_hi(uc.x)*ubf_hi(ug.x));
    o.y = pack2(ubf_lo(uc.y)*ubf_lo(ug.y), ubf_hi(uc.y)*ubf_hi(ug.y));
    o.z = pack2(ubf_lo(uc.z)*ubf_lo(ug.z), ubf_hi(uc.z)*ubf_hi(ug.z));
    o.w = pack2(ubf_lo(uc.w)*ubf_lo(ug.w), ubf_hi(uc.w)*ubf_hi(ug.w));
    *(uint4*)(ccb + r*512 + kd) = o;
  }
  __syncthreads();

  const int t = r0 >> 6, b0r = r0 & 63;
  const long rbf = (long)r0 + rw;
  const long rbr = (long)(1023 - t)*64 + b0r + rw;
  u16* stg = gb + wv*512;

  for (int p2=0; p2<6; p2++){
    const int nt = nq*12 + p2*2;
    const int j0 = nt * 16;
    const bool isf = (j0 < 384);
    const u16* wbP = isf ? wfbP : wrbP;
    const float* bi = isf ? bihf : bihr;
    const int jb = isf ? j0 : (j0 - 384);
    const int cbA = jb >> 4, cbB = cbA + 1;
    const long rbase = isf ? rbf : rbr;
    u16* GIo = isf ? GIf : GIr;
    const int c0 = jb + (l & 15), c1 = c0 + 16;
    const u16* b0p = wbP + ((long)cbA*16*64 + (long)l)*8;
    const u16* b1p = wbP + ((long)cbB*16*64 + (long)l)*8;
    f32x4 a0 = {0.f,0.f,0.f,0.f}, a1 = {0.f,0.f,0.f,0.f};
    #pragma unroll
    for (int kk=0; kk<16; kk++){
      const bf16x8 av = *(const bf16x8*)(abase + ((kk*32 + kgrp) ^ swz));
      const bf16x8 b0 = *(const bf16x8*)(b0p + kk*512);
      const bf16x8 b1 = *(const bf16x8*)(b1p + kk*512);
      a0 = mfma16(av, b0, a0);
      a1 = mfma16(av, b1, a1);
    }
    const float bi0 = bi[c0], bi1 = bi[c1];
    #pragma unroll
    for (int i=0;i<4;i++){
      stg[((l>>4)*4+i)*16 + (l&15)]       = bfu(a0[i] + bi0);
      stg[256 + ((l>>4)*4+i)*16 + (l&15)] = bfu(a1[i] + bi1);
    }
    {
      const int rr = l >> 2, q = l & 3;
      const uint2 v0 = *(const uint2*)(stg + rr*16 + q*4);
      const uint2 v1 = *(const uint2*)(stg + 256 + rr*16 + q*4);
      *(uint2*)(GIo + (rbase + rr)*384 + jb      + q*4) = v0;
      *(uint2*)(GIo + (rbase + rr)*384 + jb + 16 + q*4) = v1;
    }
  }
}

// ---------------------------------------------------------------------------
// K4 (R8 structure, depth-1 prefetch): GRU recurrences.
// 128 blocks = (dir, b), 512 threads; seg-split partial dots via LDS.
// ---------------------------------------------------------------------------
__global__ __launch_bounds__(512,2) void k_gru(
      const u16* __restrict__ GIf, const u16* __restrict__ GIr,
      const float* __restrict__ whhf, const float* __restrict__ bhhf,
      const float* __restrict__ whhr, const float* __restrict__ bhhr,
      const float* __restrict__ h0f, const float* __restrict__ h0r,
      float* __restrict__ out){
  const int d = blockIdx.x >> 6, b = blockIdx.x & 63;
  const u16* GI = d ? GIr  : GIf;
  const float* whh = d ? whhr : whhf;
  const float* bhh = d ? bhhr : bhhf;
  const float* h0  = d ? h0r  : h0f;
  const int tid = threadIdx.x;
  const int seg = tid >> 7, j0 = tid & 127;
  __shared__ __align__(16) float hsh[128];
  __shared__ __align__(16) float part[4*384];

  float4 wR[8], wZ[8], wN[8];
  {
    const float4* r0p = (const float4*)(whh + (long)(j0      )*128 + seg*32);
    const float4* r1p = (const float4*)(whh + (long)(j0 + 128)*128 + seg*32);
    const float4* r2p = (const float4*)(whh + (long)(j0 + 256)*128 + seg*32);
    #pragma unroll
    for (int q=0;q<8;q++){ wR[q]=r0p[q]; wZ[q]=r1p[q]; wN[q]=r2p[q]; }
  }
  float bjr=0.f, bjz=0.f, bjn=0.f, hold=0.f;
  float gr_n=0.f, gz_n=0.f, gn_n=0.f;
  if (tid < 128){
    hsh[tid] = hold = h0[b*128 + tid];
    bjr = bhh[tid]; bjz = bhh[tid+128]; bjn = bhh[tid+256];
    gr_n = ubf(GI[(long)b*384 + tid]);
    gz_n = ubf(GI[(long)b*384 + tid + 128]);
    gn_n = ubf(GI[(long)b*384 + tid + 256]);
  }
  __syncthreads();

  for (int t=0; t<1024; t++){
    {
      float aR=0.f, aZ=0.f, aN=0.f;
      const float4* hseg = (const float4*)(hsh + seg*32);
      #pragma unroll
      for (int q=0;q<8;q++){
        const float4 hv = hseg[q];
        aR += wR[q].x*hv.x + wR[q].y*hv.y + wR[q].z*hv.z + wR[q].w*hv.w;
        aZ += wZ[q].x*hv.x + wZ[q].y*hv.y + wZ[q].z*hv.z + wZ[q].w*hv.w;
        aN += wN[q].x*hv.x + wN[q].y*hv.y + wN[q].z*hv.z + wN[q].w*hv.w;
      }
      part[seg*384 + j0]       = aR;
      part[seg*384 + j0 + 128] = aZ;
      part[seg*384 + j0 + 256] = aN;
    }
    __syncthreads();
    if (tid < 128){
      const float gr = gr_n, gz = gz_n, gn = gn_n;
      if (t < 1023){
        const long base = ((long)(t+1)*64 + b)*384 + tid;
        gr_n = ubf(GI[base]); gz_n = ubf(GI[base+128]); gn_n = ubf(GI[base+256]);
      }
      const float ghr = bjr + ((part[tid]       + part[384+tid])       + (part[768+tid]       + part[1152+tid]));
      const float ghz = bjz + ((part[tid+128]   + part[384+tid+128])   + (part[768+tid+128]   + part[1152+tid+128]));
      const float ghn = bjn + ((part[tid+256]   + part[384+tid+256])   + (part[768+tid+256]   + part[1152+tid+256]));
      const float r = sigmoidf_(gr + ghr);
      const float z = sigmoidf_(gz + ghz);
      const float n = tanhf_fast(gn + r*ghn);
      const float hnew = (1.f - z)*n + z*hold;
      hold = hnew;
      hsh[tid] = hnew;
      out[((long)t*64 + b)*256 + d*128 + tid] = hnew;
    }
    __syncthreads();
  }
}

__global__ void k_sentinel(float* out){ out[0] = 1.0e6f; }

// ---------------------------------------------------------------------------
extern "C" void kernel_launch(void* const* d_in, const int* in_sizes, int n_in,
                              void* d_out, int out_size, void* d_ws, size_t ws_size,
                              hipStream_t stream){
  const float* passEnc = (const float*)d_in[0];
  const float* Wp_w  = (const float*)d_in[1];
  const float* Wp_b  = (const float*)d_in[2];
  const float* Wph_w = (const float*)d_in[3];
  const float* Wph_b = (const float*)d_in[4];
  const float* Wg_w  = (const float*)d_in[5];
  const float* Wg_b  = (const float*)d_in[6];
  const float* Vt    = (const float*)d_in[7];
  const float* wih_f = (const float*)d_in[8];
  const float* whh_f = (const float*)d_in[9];
  const float* bih_f = (const float*)d_in[10];
  const float* bhh_f = (const float*)d_in[11];
  const float* wih_r = (const float*)d_in[12];
  const float* whh_r = (const float*)d_in[13];
  const float* bih_r = (const float*)d_in[14];
  const float* bhh_r = (const float*)d_in[15];
  const float* h0f   = (const float*)d_in[16];
  const float* h0r   = (const float*)d_in[17];
  float* out = (float*)d_out;

  // Workspace (128 MiB): GIf bf16 | GIr bf16 | C bf16; E/F f32 overlay GIf/GIr.
  // Packed weights (1.31 MB) + transposed Wp/Wph (256 KB) live in the front of
  // d_out; k_gru overwrites ALL of d_out afterwards.
  const size_t NEED = 134217728ull;
  if (ws_size < NEED){ k_sentinel<<<1,1,0,stream>>>(out); return; }
  char* base = (char*)d_ws;
  u16* GIf = (u16*)base;
  u16* GIr = (u16*)(base + 50331648ull);
  u16* C   = (u16*)(base + 100663296ull);
  float* E = (float*)base;
  float* F = (float*)(base + 33554432ull);
  u16* wgbP = (u16*)d_out;
  u16* wfbP = wgbP + 262144;
  u16* wrbP = wfbP + 196608;
  float* WpT  = (float*)(wrbP + 196608);
  float* WphT = WpT + 32768;

  k_prep <<<576,  256, 0, stream>>>(Wg_w, wih_f, wih_r, Wp_w, Wph_w,
                                    wgbP, wfbP, wrbP, WpT, WphT);
  k_proj <<<4096, 256, 0, stream>>>(passEnc, WpT, Wp_b, WphT, Wph_b, E, F);
  k_attn <<<1024, 512, 0, stream>>>(passEnc, E, F, Vt, C);
  k_gates<<<2048, 512, 0, stream>>>(passEnc, C, wgbP, Wg_b,
                                    wfbP, bih_f, wrbP, bih_r, GIf, GIr);
  k_gru  <<<128,  512, 0, stream>>>(GIf, GIr, whh_f, bhh_f, whh_r, bhh_r, h0f, h0r, out);
}